// Round 2
// baseline (511.938 us; speedup 1.0000x reference)
//
#include <hip/hip_runtime.h>
#include <hip/hip_bf16.h>
#include <stdint.h>

// CausalMultiHeadAttention: B=4 S=2048 C=768 H=6 D=128
// Pipeline: cast(x,wT) -> GEMM1 qkv(bf16) -> flash-attn -> GEMM2 -> f32 out
#define SS 2048
#define CC 768
#define C3 2304

typedef float f32x4 __attribute__((ext_vector_type(4)));
typedef short s16x8 __attribute__((ext_vector_type(8)));

__device__ __forceinline__ unsigned short f2bf(float f) {
  union { float f; unsigned int u; } v; v.f = f;
  unsigned int r = (v.u + 0x7FFFu + ((v.u >> 16) & 1u)) >> 16;
  return (unsigned short)r;
}

__device__ __forceinline__ s16x8 ld8(const unsigned short* p) {
  return *reinterpret_cast<const s16x8*>(p);
}

__global__ __launch_bounds__(256) void cast_bf16_kernel(
    const float* __restrict__ src, unsigned short* __restrict__ dst, int n4) {
  int i = blockIdx.x * 256 + threadIdx.x;
  if (i < n4) {
    float4 v = reinterpret_cast<const float4*>(src)[i];
    ushort4 o;
    o.x = f2bf(v.x); o.y = f2bf(v.y); o.z = f2bf(v.z); o.w = f2bf(v.w);
    reinterpret_cast<ushort4*>(dst)[i] = o;
  }
}

// src [R][C] f32 -> dst [C][R] bf16
__global__ __launch_bounds__(256) void transpose_cast_kernel(
    const float* __restrict__ src, unsigned short* __restrict__ dst, int R, int C) {
  __shared__ float tile[32][33];
  int c0 = blockIdx.x * 32, r0 = blockIdx.y * 32;
  int tx = threadIdx.x & 31, ty = threadIdx.x >> 5;  // ty in [0,8)
  #pragma unroll
  for (int i = 0; i < 32; i += 8)
    tile[ty + i][tx] = src[(size_t)(r0 + ty + i) * C + c0 + tx];
  __syncthreads();
  #pragma unroll
  for (int i = 0; i < 32; i += 8)
    dst[(size_t)(c0 + ty + i) * R + r0 + tx] = f2bf(tile[tx][ty + i]);
}

// C[m][n] = sum_k A[m][k]*Bt[n][k] + bias[n].  A:[M,K] bf16, Bt:[N,K] bf16.
// Block: 256 thr = 4 waves (2x2), each wave 32x32 via 2x2 MFMA 16x16x32.
template <int OUT_BF16>
__global__ __launch_bounds__(256) void gemm_bt_kernel(
    const unsigned short* __restrict__ A, const unsigned short* __restrict__ Bt,
    const float* __restrict__ bias, void* __restrict__ out, int M, int N, int K) {
  const int lane = threadIdx.x & 63, w = threadIdx.x >> 6;
  const int m_base = blockIdx.y * 64 + (w >> 1) * 32;
  const int n_base = blockIdx.x * 64 + (w & 1) * 32;
  const int lm = lane & 15, lk = (lane >> 4) * 8;
  f32x4 acc[2][2] = {};
  const unsigned short* a0 = A + (size_t)(m_base + lm) * K + lk;
  const unsigned short* a1 = a0 + (size_t)16 * K;
  const unsigned short* b0 = Bt + (size_t)(n_base + lm) * K + lk;
  const unsigned short* b1 = b0 + (size_t)16 * K;
  for (int k0 = 0; k0 < K; k0 += 32) {
    s16x8 av0 = ld8(a0 + k0), av1 = ld8(a1 + k0);
    s16x8 bv0 = ld8(b0 + k0), bv1 = ld8(b1 + k0);
    acc[0][0] = __builtin_amdgcn_mfma_f32_16x16x32_bf16(av0, bv0, acc[0][0], 0, 0, 0);
    acc[0][1] = __builtin_amdgcn_mfma_f32_16x16x32_bf16(av0, bv1, acc[0][1], 0, 0, 0);
    acc[1][0] = __builtin_amdgcn_mfma_f32_16x16x32_bf16(av1, bv0, acc[1][0], 0, 0, 0);
    acc[1][1] = __builtin_amdgcn_mfma_f32_16x16x32_bf16(av1, bv1, acc[1][1], 0, 0, 0);
  }
  #pragma unroll
  for (int i = 0; i < 2; ++i) {
    #pragma unroll
    for (int j = 0; j < 2; ++j) {
      int row = m_base + i * 16 + (lane >> 4) * 4;
      int col = n_base + j * 16 + lm;
      float bs = bias[col];
      #pragma unroll
      for (int r = 0; r < 4; ++r) {
        float v = acc[i][j][r] + bs;
        if (OUT_BF16)
          ((unsigned short*)out)[(size_t)(row + r) * N + col] = f2bf(v);
        else
          ((float*)out)[(size_t)(row + r) * N + col] = v;
      }
    }
  }
}

// Flash attention, causal. Block = 4 waves, q-tile 64 (16 rows/wave), kv-tile 32.
// QK^T computed swapped (S^T = K.Q^T) so softmax stats live at col=lane&15.
__global__ __launch_bounds__(256) void attn_kernel(
    const unsigned short* __restrict__ qkv, unsigned short* __restrict__ aout) {
  const int qt = blockIdx.x, h = blockIdx.y, b = blockIdx.z;
  const int tid = threadIdx.x, lane = tid & 63, w = tid >> 6;
  const int q0 = qt * 64, wq0 = q0 + w * 16;
  const int lm = lane & 15, lg = lane >> 4;
  __shared__ unsigned short vt[128 * 32];     // V^T tile [d][n], n XOR-swizzled
  __shared__ unsigned short pb[4][16 * 48];   // per-wave P [m][n], stride 48

  const unsigned short* base = qkv + (size_t)b * SS * C3;
  s16x8 qf[4];
  {
    const unsigned short* qp = base + (size_t)(wq0 + lm) * C3 + h * 128 + lg * 8;
    #pragma unroll
    for (int ks = 0; ks < 4; ++ks) qf[ks] = ld8(qp + ks * 32);
  }
  f32x4 oacc[8] = {};
  float m_run = -1e30f, l_run = 0.0f;
  const int ntiles = (q0 + 64) >> 5;
  for (int t = 0; t < ntiles; ++t) {
    const int n0 = t * 32;
    __syncthreads();
    #pragma unroll
    for (int i = 0; i < 2; ++i) {
      int c = tid + 256 * i;
      int vr = c >> 4, vc = (c & 15) * 8;
      s16x8 v = ld8(base + (size_t)(n0 + vr) * C3 + 2 * CC + h * 128 + vc);
      #pragma unroll
      for (int j = 0; j < 8; ++j) {
        int d = vc + j;
        vt[d * 32 + (vr ^ (((d >> 3) & 3) << 3))] = (unsigned short)v[j];
      }
    }
    __syncthreads();
    if (n0 <= wq0 + 15) {
      f32x4 sacc[2] = {};
      #pragma unroll
      for (int nsub = 0; nsub < 2; ++nsub) {
        const unsigned short* kp =
            base + (size_t)(n0 + nsub * 16 + lm) * C3 + CC + h * 128 + lg * 8;
        #pragma unroll
        for (int ks = 0; ks < 4; ++ks) {
          s16x8 kf = ld8(kp + ks * 32);
          sacc[nsub] = __builtin_amdgcn_mfma_f32_16x16x32_bf16(kf, qf[ks], sacc[nsub], 0, 0, 0);
        }
      }
      const int qg = wq0 + lm;
      const bool full = (n0 + 31 <= wq0);
      float xs[2][4];
      float tmax = -1e30f;
      #pragma unroll
      for (int nsub = 0; nsub < 2; ++nsub) {
        #pragma unroll
        for (int r = 0; r < 4; ++r) {
          int ng = n0 + nsub * 16 + lg * 4 + r;
          float x = sacc[nsub][r] * 0.08838834764831845f;  // 1/sqrt(128)
          if (!full && ng > qg) x = -1e30f;
          xs[nsub][r] = x;
          tmax = fmaxf(tmax, x);
        }
      }
      tmax = fmaxf(tmax, __shfl_xor(tmax, 16));
      tmax = fmaxf(tmax, __shfl_xor(tmax, 32));
      float m_new = fmaxf(m_run, tmax);
      float psum = 0.f;
      #pragma unroll
      for (int nsub = 0; nsub < 2; ++nsub) {
        #pragma unroll
        for (int r = 0; r < 4; ++r) {
          float p = __expf(xs[nsub][r] - m_new);
          psum += p;
          pb[w][lm * 48 + nsub * 16 + lg * 4 + r] = f2bf(p);
        }
      }
      psum += __shfl_xor(psum, 16);
      psum += __shfl_xor(psum, 32);
      float resc = __expf(m_run - m_new);
      l_run = l_run * resc + psum;
      m_run = m_new;
      #pragma unroll
      for (int r = 0; r < 4; ++r) {
        float s = __shfl(resc, lg * 4 + r);
        #pragma unroll
        for (int dsub = 0; dsub < 8; ++dsub) oacc[dsub][r] *= s;
      }
      s16x8 pf = ld8(&pb[w][lm * 48 + lg * 8]);
      #pragma unroll
      for (int dsub = 0; dsub < 8; ++dsub) {
        int d = dsub * 16 + lm;
        s16x8 vf = ld8(&vt[d * 32 + ((lg * 8) ^ (((d >> 3) & 3) << 3))]);
        oacc[dsub] = __builtin_amdgcn_mfma_f32_16x16x32_bf16(pf, vf, oacc[dsub], 0, 0, 0);
      }
    }
  }
  float linv[4];
  #pragma unroll
  for (int r = 0; r < 4; ++r) linv[r] = 1.0f / __shfl(l_run, lg * 4 + r);
  #pragma unroll
  for (int dsub = 0; dsub < 8; ++dsub) {
    int col = h * 128 + dsub * 16 + lm;
    #pragma unroll
    for (int r = 0; r < 4; ++r) {
      int row = wq0 + lg * 4 + r;
      aout[(size_t)(b * SS + row) * CC + col] = f2bf(oacc[dsub][r] * linv[r]);
    }
  }
}

extern "C" void kernel_launch(void* const* d_in, const int* in_sizes, int n_in,
                              void* d_out, int out_size, void* d_ws, size_t ws_size,
                              hipStream_t stream) {
  const float* x      = (const float*)d_in[0];
  const float* w_attn = (const float*)d_in[1];
  const float* b_attn = (const float*)d_in[2];
  const float* w_proj = (const float*)d_in[3];
  const float* b_proj = (const float*)d_in[4];
  float* out = (float*)d_out;

  const size_t M = 4 * (size_t)SS;  // 8192 tokens
  unsigned short* ws = (unsigned short*)d_ws;
  unsigned short* xb   = ws;                       // [8192,768] bf16 (reused as aout)
  unsigned short* waT  = xb + M * CC;              // [2304,768] bf16
  unsigned short* wpT  = waT + (size_t)C3 * CC;    // [768,768] bf16
  unsigned short* qkv  = wpT + (size_t)CC * CC;    // [8192,2304] bf16
  unsigned short* aout = xb;                       // alias: xb dead after GEMM1

  int n4 = (int)(M * CC / 4);
  cast_bf16_kernel<<<(n4 + 255) / 256, 256, 0, stream>>>(x, xb, n4);
  transpose_cast_kernel<<<dim3(C3 / 32, CC / 32), 256, 0, stream>>>(w_attn, waT, CC, C3);
  transpose_cast_kernel<<<dim3(CC / 32, CC / 32), 256, 0, stream>>>(w_proj, wpT, CC, CC);

  gemm_bt_kernel<1><<<dim3(C3 / 64, M / 64), 256, 0, stream>>>(
      xb, waT, b_attn, (void*)qkv, (int)M, C3, CC);

  attn_kernel<<<dim3(SS / 64, 6, 4), 256, 0, stream>>>(qkv, aout);

  gemm_bt_kernel<0><<<dim3(CC / 64, M / 64), 256, 0, stream>>>(
      aout, wpT, b_proj, (void*)out, (int)M, CC, CC);
}

// Round 3
// 511.314 us; speedup vs baseline: 1.0012x; 1.0012x over previous
//
#include <hip/hip_runtime.h>
#include <hip/hip_bf16.h>
#include <stdint.h>

// CausalMultiHeadAttention: B=4 S=2048 C=768 H=6 D=128
// Pipeline: cast(x,wT) -> GEMM1 qkv(bf16) -> flash-attn -> GEMM2 -> f32 out
#define SS 2048
#define CC 768
#define C3 2304

typedef float f32x4 __attribute__((ext_vector_type(4)));
typedef short s16x8 __attribute__((ext_vector_type(8)));

__device__ __forceinline__ unsigned short f2bf(float f) {
  union { float f; unsigned int u; } v; v.f = f;
  unsigned int r = (v.u + 0x7FFFu + ((v.u >> 16) & 1u)) >> 16;
  return (unsigned short)r;
}

__device__ __forceinline__ s16x8 ld8(const unsigned short* p) {
  return *reinterpret_cast<const s16x8*>(p);
}

__global__ __launch_bounds__(256) void cast_bf16_kernel(
    const float* __restrict__ src, unsigned short* __restrict__ dst, int n4) {
  int i = blockIdx.x * 256 + threadIdx.x;
  if (i < n4) {
    float4 v = reinterpret_cast<const float4*>(src)[i];
    ushort4 o;
    o.x = f2bf(v.x); o.y = f2bf(v.y); o.z = f2bf(v.z); o.w = f2bf(v.w);
    reinterpret_cast<ushort4*>(dst)[i] = o;
  }
}

// src [R][C] f32 -> dst [C][R] bf16
__global__ __launch_bounds__(256) void transpose_cast_kernel(
    const float* __restrict__ src, unsigned short* __restrict__ dst, int R, int C) {
  __shared__ float tile[32][33];
  int c0 = blockIdx.x * 32, r0 = blockIdx.y * 32;
  int tx = threadIdx.x & 31, ty = threadIdx.x >> 5;  // ty in [0,8)
  #pragma unroll
  for (int i = 0; i < 32; i += 8)
    tile[ty + i][tx] = src[(size_t)(r0 + ty + i) * C + c0 + tx];
  __syncthreads();
  #pragma unroll
  for (int i = 0; i < 32; i += 8)
    dst[(size_t)(c0 + ty + i) * R + r0 + tx] = f2bf(tile[tx][ty + i]);
}

// C[m][n] = sum_k A[m][k]*Bt[n][k] + bias[n].  A:[M,K] bf16, Bt:[N,K] bf16.
// Block: 256 thr = 4 waves (2x2), each wave 32x32 via 2x2 MFMA 16x16x32.
template <int OUT_BF16>
__global__ __launch_bounds__(256) void gemm_bt_kernel(
    const unsigned short* __restrict__ A, const unsigned short* __restrict__ Bt,
    const float* __restrict__ bias, void* __restrict__ out, int M, int N, int K) {
  const int lane = threadIdx.x & 63, w = threadIdx.x >> 6;
  const int m_base = blockIdx.y * 64 + (w >> 1) * 32;
  const int n_base = blockIdx.x * 64 + (w & 1) * 32;
  const int lm = lane & 15, lk = (lane >> 4) * 8;
  f32x4 acc[2][2] = {};
  const unsigned short* a0 = A + (size_t)(m_base + lm) * K + lk;
  const unsigned short* a1 = a0 + (size_t)16 * K;
  const unsigned short* b0 = Bt + (size_t)(n_base + lm) * K + lk;
  const unsigned short* b1 = b0 + (size_t)16 * K;
  for (int k0 = 0; k0 < K; k0 += 32) {
    s16x8 av0 = ld8(a0 + k0), av1 = ld8(a1 + k0);
    s16x8 bv0 = ld8(b0 + k0), bv1 = ld8(b1 + k0);
    acc[0][0] = __builtin_amdgcn_mfma_f32_16x16x32_bf16(av0, bv0, acc[0][0], 0, 0, 0);
    acc[0][1] = __builtin_amdgcn_mfma_f32_16x16x32_bf16(av0, bv1, acc[0][1], 0, 0, 0);
    acc[1][0] = __builtin_amdgcn_mfma_f32_16x16x32_bf16(av1, bv0, acc[1][0], 0, 0, 0);
    acc[1][1] = __builtin_amdgcn_mfma_f32_16x16x32_bf16(av1, bv1, acc[1][1], 0, 0, 0);
  }
  #pragma unroll
  for (int i = 0; i < 2; ++i) {
    #pragma unroll
    for (int j = 0; j < 2; ++j) {
      int row = m_base + i * 16 + (lane >> 4) * 4;
      int col = n_base + j * 16 + lm;
      float bs = bias[col];
      #pragma unroll
      for (int r = 0; r < 4; ++r) {
        float v = acc[i][j][r] + bs;
        if (OUT_BF16)
          ((unsigned short*)out)[(size_t)(row + r) * N + col] = f2bf(v);
        else
          ((float*)out)[(size_t)(row + r) * N + col] = v;
      }
    }
  }
}

// Flash attention, causal. Block = 4 waves, q-tile 64 (16 rows/wave), kv-tile 32.
// QK^T computed swapped (S^T = K.Q^T) so softmax stats live at col=lane&15.
__global__ __launch_bounds__(256) void attn_kernel(
    const unsigned short* __restrict__ qkv, unsigned short* __restrict__ aout) {
  const int qt = blockIdx.x, h = blockIdx.y, b = blockIdx.z;
  const int tid = threadIdx.x, lane = tid & 63, w = tid >> 6;
  const int q0 = qt * 64, wq0 = q0 + w * 16;
  const int lm = lane & 15, lg = lane >> 4;
  __shared__ unsigned short vt[128 * 32];     // V^T tile [d][n], n XOR-swizzled
  __shared__ unsigned short pb[4][16 * 48];   // per-wave P [m][n], stride 48

  const unsigned short* base = qkv + (size_t)b * SS * C3;
  s16x8 qf[4];
  {
    const unsigned short* qp = base + (size_t)(wq0 + lm) * C3 + h * 128 + lg * 8;
    #pragma unroll
    for (int ks = 0; ks < 4; ++ks) qf[ks] = ld8(qp + ks * 32);
  }
  f32x4 oacc[8] = {};
  float m_run = -1e30f, l_run = 0.0f;
  const int ntiles = (q0 + 64) >> 5;
  for (int t = 0; t < ntiles; ++t) {
    const int n0 = t * 32;
    __syncthreads();
    #pragma unroll
    for (int i = 0; i < 2; ++i) {
      int c = tid + 256 * i;
      int vr = c >> 4, vc = (c & 15) * 8;
      s16x8 v = ld8(base + (size_t)(n0 + vr) * C3 + 2 * CC + h * 128 + vc);
      #pragma unroll
      for (int j = 0; j < 8; ++j) {
        int d = vc + j;
        vt[d * 32 + (vr ^ (((d >> 3) & 3) << 3))] = (unsigned short)v[j];
      }
    }
    __syncthreads();
    if (n0 <= wq0 + 15) {
      f32x4 sacc[2] = {};
      #pragma unroll
      for (int nsub = 0; nsub < 2; ++nsub) {
        const unsigned short* kp =
            base + (size_t)(n0 + nsub * 16 + lm) * C3 + CC + h * 128 + lg * 8;
        #pragma unroll
        for (int ks = 0; ks < 4; ++ks) {
          s16x8 kf = ld8(kp + ks * 32);
          sacc[nsub] = __builtin_amdgcn_mfma_f32_16x16x32_bf16(kf, qf[ks], sacc[nsub], 0, 0, 0);
        }
      }
      const int qg = wq0 + lm;
      const bool full = (n0 + 31 <= wq0);
      float xs[2][4];
      float tmax = -1e30f;
      #pragma unroll
      for (int nsub = 0; nsub < 2; ++nsub) {
        #pragma unroll
        for (int r = 0; r < 4; ++r) {
          int ng = n0 + nsub * 16 + lg * 4 + r;
          float x = sacc[nsub][r] * 0.08838834764831845f;  // 1/sqrt(128)
          if (!full && ng > qg) x = -1e30f;
          xs[nsub][r] = x;
          tmax = fmaxf(tmax, x);
        }
      }
      tmax = fmaxf(tmax, __shfl_xor(tmax, 16));
      tmax = fmaxf(tmax, __shfl_xor(tmax, 32));
      float m_new = fmaxf(m_run, tmax);
      float psum = 0.f;
      #pragma unroll
      for (int nsub = 0; nsub < 2; ++nsub) {
        #pragma unroll
        for (int r = 0; r < 4; ++r) {
          float p = __expf(xs[nsub][r] - m_new);
          psum += p;
          pb[w][lm * 48 + nsub * 16 + lg * 4 + r] = f2bf(p);
        }
      }
      psum += __shfl_xor(psum, 16);
      psum += __shfl_xor(psum, 32);
      float resc = __expf(m_run - m_new);
      l_run = l_run * resc + psum;
      m_run = m_new;
      #pragma unroll
      for (int r = 0; r < 4; ++r) {
        float s = __shfl(resc, lg * 4 + r);
        #pragma unroll
        for (int dsub = 0; dsub < 8; ++dsub) oacc[dsub][r] *= s;
      }
      s16x8 pf = ld8(&pb[w][lm * 48 + lg * 8]);
      #pragma unroll
      for (int dsub = 0; dsub < 8; ++dsub) {
        int d = dsub * 16 + lm;
        s16x8 vf = ld8(&vt[d * 32 + ((lg * 8) ^ (((d >> 3) & 3) << 3))]);
        oacc[dsub] = __builtin_amdgcn_mfma_f32_16x16x32_bf16(pf, vf, oacc[dsub], 0, 0, 0);
      }
    }
  }
  float linv[4];
  #pragma unroll
  for (int r = 0; r < 4; ++r) linv[r] = 1.0f / __shfl(l_run, lg * 4 + r);
  #pragma unroll
  for (int dsub = 0; dsub < 8; ++dsub) {
    int col = h * 128 + dsub * 16 + lm;
    #pragma unroll
    for (int r = 0; r < 4; ++r) {
      int row = wq0 + lg * 4 + r;
      aout[(size_t)(b * SS + row) * CC + col] = f2bf(oacc[dsub][r] * linv[r]);
    }
  }
}

extern "C" void kernel_launch(void* const* d_in, const int* in_sizes, int n_in,
                              void* d_out, int out_size, void* d_ws, size_t ws_size,
                              hipStream_t stream) {
  const float* x      = (const float*)d_in[0];
  const float* w_attn = (const float*)d_in[1];
  const float* b_attn = (const float*)d_in[2];
  const float* w_proj = (const float*)d_in[3];
  const float* b_proj = (const float*)d_in[4];
  float* out = (float*)d_out;

  const size_t M = 4 * (size_t)SS;  // 8192 tokens
  unsigned short* ws = (unsigned short*)d_ws;
  unsigned short* xb   = ws;                       // [8192,768] bf16 (reused as aout)
  unsigned short* waT  = xb + M * CC;              // [2304,768] bf16
  unsigned short* wpT  = waT + (size_t)C3 * CC;    // [768,768] bf16
  unsigned short* qkv  = wpT + (size_t)CC * CC;    // [8192,2304] bf16
  unsigned short* aout = xb;                       // alias: xb dead after GEMM1

  int n4 = (int)(M * CC / 4);
  cast_bf16_kernel<<<(n4 + 255) / 256, 256, 0, stream>>>(x, xb, n4);
  transpose_cast_kernel<<<dim3(C3 / 32, CC / 32), 256, 0, stream>>>(w_attn, waT, CC, C3);
  transpose_cast_kernel<<<dim3(CC / 32, CC / 32), 256, 0, stream>>>(w_proj, wpT, CC, CC);

  gemm_bt_kernel<1><<<dim3(C3 / 64, M / 64), 256, 0, stream>>>(
      xb, waT, b_attn, (void*)qkv, (int)M, C3, CC);

  attn_kernel<<<dim3(SS / 64, 6, 4), 256, 0, stream>>>(qkv, aout);

  gemm_bt_kernel<0><<<dim3(CC / 64, M / 64), 256, 0, stream>>>(
      aout, wpT, b_proj, (void*)out, (int)M, CC, CC);
}

// Round 4
// 510.905 us; speedup vs baseline: 1.0020x; 1.0008x over previous
//
#include <hip/hip_runtime.h>
#include <hip/hip_bf16.h>
#include <stdint.h>

// CausalMultiHeadAttention: B=4 S=2048 C=768 H=6 D=128
// Pipeline: cast(x,wT) -> GEMM1 qkv(bf16) -> flash-attn -> GEMM2 -> f32 out
#define SS 2048
#define CC 768
#define C3 2304

typedef float f32x4 __attribute__((ext_vector_type(4)));
typedef short s16x8 __attribute__((ext_vector_type(8)));

__device__ __forceinline__ unsigned short f2bf(float f) {
  union { float f; unsigned int u; } v; v.f = f;
  unsigned int r = (v.u + 0x7FFFu + ((v.u >> 16) & 1u)) >> 16;
  return (unsigned short)r;
}

__device__ __forceinline__ s16x8 ld8(const unsigned short* p) {
  return *reinterpret_cast<const s16x8*>(p);
}

__global__ __launch_bounds__(256) void cast_bf16_kernel(
    const float* __restrict__ src, unsigned short* __restrict__ dst, int n4) {
  int i = blockIdx.x * 256 + threadIdx.x;
  if (i < n4) {
    float4 v = reinterpret_cast<const float4*>(src)[i];
    ushort4 o;
    o.x = f2bf(v.x); o.y = f2bf(v.y); o.z = f2bf(v.z); o.w = f2bf(v.w);
    reinterpret_cast<ushort4*>(dst)[i] = o;
  }
}

// src [R][C] f32 -> dst [C][R] bf16
__global__ __launch_bounds__(256) void transpose_cast_kernel(
    const float* __restrict__ src, unsigned short* __restrict__ dst, int R, int C) {
  __shared__ float tile[32][33];
  int c0 = blockIdx.x * 32, r0 = blockIdx.y * 32;
  int tx = threadIdx.x & 31, ty = threadIdx.x >> 5;  // ty in [0,8)
  #pragma unroll
  for (int i = 0; i < 32; i += 8)
    tile[ty + i][tx] = src[(size_t)(r0 + ty + i) * C + c0 + tx];
  __syncthreads();
  #pragma unroll
  for (int i = 0; i < 32; i += 8)
    dst[(size_t)(c0 + ty + i) * R + r0 + tx] = f2bf(tile[tx][ty + i]);
}

// C[m][n] = sum_k A[m][k]*Bt[n][k] + bias[n].  A:[M,K] bf16, Bt:[N,K] bf16.
// Block: 256 thr = 4 waves (2x2), each wave 32x32 via 2x2 MFMA 16x16x32.
template <int OUT_BF16>
__global__ __launch_bounds__(256) void gemm_bt_kernel(
    const unsigned short* __restrict__ A, const unsigned short* __restrict__ Bt,
    const float* __restrict__ bias, void* __restrict__ out, int M, int N, int K) {
  const int lane = threadIdx.x & 63, w = threadIdx.x >> 6;
  const int m_base = blockIdx.y * 64 + (w >> 1) * 32;
  const int n_base = blockIdx.x * 64 + (w & 1) * 32;
  const int lm = lane & 15, lk = (lane >> 4) * 8;
  f32x4 acc[2][2] = {};
  const unsigned short* a0 = A + (size_t)(m_base + lm) * K + lk;
  const unsigned short* a1 = a0 + (size_t)16 * K;
  const unsigned short* b0 = Bt + (size_t)(n_base + lm) * K + lk;
  const unsigned short* b1 = b0 + (size_t)16 * K;
  for (int k0 = 0; k0 < K; k0 += 32) {
    s16x8 av0 = ld8(a0 + k0), av1 = ld8(a1 + k0);
    s16x8 bv0 = ld8(b0 + k0), bv1 = ld8(b1 + k0);
    acc[0][0] = __builtin_amdgcn_mfma_f32_16x16x32_bf16(av0, bv0, acc[0][0], 0, 0, 0);
    acc[0][1] = __builtin_amdgcn_mfma_f32_16x16x32_bf16(av0, bv1, acc[0][1], 0, 0, 0);
    acc[1][0] = __builtin_amdgcn_mfma_f32_16x16x32_bf16(av1, bv0, acc[1][0], 0, 0, 0);
    acc[1][1] = __builtin_amdgcn_mfma_f32_16x16x32_bf16(av1, bv1, acc[1][1], 0, 0, 0);
  }
  #pragma unroll
  for (int i = 0; i < 2; ++i) {
    #pragma unroll
    for (int j = 0; j < 2; ++j) {
      int row = m_base + i * 16 + (lane >> 4) * 4;
      int col = n_base + j * 16 + lm;
      float bs = bias[col];
      #pragma unroll
      for (int r = 0; r < 4; ++r) {
        float v = acc[i][j][r] + bs;
        if (OUT_BF16)
          ((unsigned short*)out)[(size_t)(row + r) * N + col] = f2bf(v);
        else
          ((float*)out)[(size_t)(row + r) * N + col] = v;
      }
    }
  }
}

// Flash attention, causal. Block = 4 waves, q-tile 64 (16 rows/wave), kv-tile 32.
// QK^T computed swapped (S^T = K.Q^T) so softmax stats live at col=lane&15.
__global__ __launch_bounds__(256) void attn_kernel(
    const unsigned short* __restrict__ qkv, unsigned short* __restrict__ aout) {
  const int qt = blockIdx.x, h = blockIdx.y, b = blockIdx.z;
  const int tid = threadIdx.x, lane = tid & 63, w = tid >> 6;
  const int q0 = qt * 64, wq0 = q0 + w * 16;
  const int lm = lane & 15, lg = lane >> 4;
  __shared__ unsigned short vt[128 * 32];     // V^T tile [d][n], n XOR-swizzled
  __shared__ unsigned short pb[4][16 * 48];   // per-wave P [m][n], stride 48

  const unsigned short* base = qkv + (size_t)b * SS * C3;
  s16x8 qf[4];
  {
    const unsigned short* qp = base + (size_t)(wq0 + lm) * C3 + h * 128 + lg * 8;
    #pragma unroll
    for (int ks = 0; ks < 4; ++ks) qf[ks] = ld8(qp + ks * 32);
  }
  f32x4 oacc[8] = {};
  float m_run = -1e30f, l_run = 0.0f;
  const int ntiles = (q0 + 64) >> 5;
  for (int t = 0; t < ntiles; ++t) {
    const int n0 = t * 32;
    __syncthreads();
    #pragma unroll
    for (int i = 0; i < 2; ++i) {
      int c = tid + 256 * i;
      int vr = c >> 4, vc = (c & 15) * 8;
      s16x8 v = ld8(base + (size_t)(n0 + vr) * C3 + 2 * CC + h * 128 + vc);
      #pragma unroll
      for (int j = 0; j < 8; ++j) {
        int d = vc + j;
        vt[d * 32 + (vr ^ (((d >> 3) & 3) << 3))] = (unsigned short)v[j];
      }
    }
    __syncthreads();
    if (n0 <= wq0 + 15) {
      f32x4 sacc[2] = {};
      #pragma unroll
      for (int nsub = 0; nsub < 2; ++nsub) {
        const unsigned short* kp =
            base + (size_t)(n0 + nsub * 16 + lm) * C3 + CC + h * 128 + lg * 8;
        #pragma unroll
        for (int ks = 0; ks < 4; ++ks) {
          s16x8 kf = ld8(kp + ks * 32);
          sacc[nsub] = __builtin_amdgcn_mfma_f32_16x16x32_bf16(kf, qf[ks], sacc[nsub], 0, 0, 0);
        }
      }
      const int qg = wq0 + lm;
      const bool full = (n0 + 31 <= wq0);
      float xs[2][4];
      float tmax = -1e30f;
      #pragma unroll
      for (int nsub = 0; nsub < 2; ++nsub) {
        #pragma unroll
        for (int r = 0; r < 4; ++r) {
          int ng = n0 + nsub * 16 + lg * 4 + r;
          float x = sacc[nsub][r] * 0.08838834764831845f;  // 1/sqrt(128)
          if (!full && ng > qg) x = -1e30f;
          xs[nsub][r] = x;
          tmax = fmaxf(tmax, x);
        }
      }
      tmax = fmaxf(tmax, __shfl_xor(tmax, 16));
      tmax = fmaxf(tmax, __shfl_xor(tmax, 32));
      float m_new = fmaxf(m_run, tmax);
      float psum = 0.f;
      #pragma unroll
      for (int nsub = 0; nsub < 2; ++nsub) {
        #pragma unroll
        for (int r = 0; r < 4; ++r) {
          float p = __expf(xs[nsub][r] - m_new);
          psum += p;
          pb[w][lm * 48 + nsub * 16 + lg * 4 + r] = f2bf(p);
        }
      }
      psum += __shfl_xor(psum, 16);
      psum += __shfl_xor(psum, 32);
      float resc = __expf(m_run - m_new);
      l_run = l_run * resc + psum;
      m_run = m_new;
      #pragma unroll
      for (int r = 0; r < 4; ++r) {
        float s = __shfl(resc, lg * 4 + r);
        #pragma unroll
        for (int dsub = 0; dsub < 8; ++dsub) oacc[dsub][r] *= s;
      }
      s16x8 pf = ld8(&pb[w][lm * 48 + lg * 8]);
      #pragma unroll
      for (int dsub = 0; dsub < 8; ++dsub) {
        int d = dsub * 16 + lm;
        s16x8 vf = ld8(&vt[d * 32 + ((lg * 8) ^ (((d >> 3) & 3) << 3))]);
        oacc[dsub] = __builtin_amdgcn_mfma_f32_16x16x32_bf16(pf, vf, oacc[dsub], 0, 0, 0);
      }
    }
  }
  float linv[4];
  #pragma unroll
  for (int r = 0; r < 4; ++r) linv[r] = 1.0f / __shfl(l_run, lg * 4 + r);
  #pragma unroll
  for (int dsub = 0; dsub < 8; ++dsub) {
    int col = h * 128 + dsub * 16 + lm;
    #pragma unroll
    for (int r = 0; r < 4; ++r) {
      int row = wq0 + lg * 4 + r;
      aout[(size_t)(b * SS + row) * CC + col] = f2bf(oacc[dsub][r] * linv[r]);
    }
  }
}

extern "C" void kernel_launch(void* const* d_in, const int* in_sizes, int n_in,
                              void* d_out, int out_size, void* d_ws, size_t ws_size,
                              hipStream_t stream) {
  const float* x      = (const float*)d_in[0];
  const float* w_attn = (const float*)d_in[1];
  const float* b_attn = (const float*)d_in[2];
  const float* w_proj = (const float*)d_in[3];
  const float* b_proj = (const float*)d_in[4];
  float* out = (float*)d_out;

  const size_t M = 4 * (size_t)SS;  // 8192 tokens
  unsigned short* ws = (unsigned short*)d_ws;
  unsigned short* xb   = ws;                       // [8192,768] bf16 (reused as aout)
  unsigned short* waT  = xb + M * CC;              // [2304,768] bf16
  unsigned short* wpT  = waT + (size_t)C3 * CC;    // [768,768] bf16
  unsigned short* qkv  = wpT + (size_t)CC * CC;    // [8192,2304] bf16
  unsigned short* aout = xb;                       // alias: xb dead after GEMM1

  int n4 = (int)(M * CC / 4);
  cast_bf16_kernel<<<(n4 + 255) / 256, 256, 0, stream>>>(x, xb, n4);
  transpose_cast_kernel<<<dim3(C3 / 32, CC / 32), 256, 0, stream>>>(w_attn, waT, CC, C3);
  transpose_cast_kernel<<<dim3(CC / 32, CC / 32), 256, 0, stream>>>(w_proj, wpT, CC, CC);

  gemm_bt_kernel<1><<<dim3(C3 / 64, M / 64), 256, 0, stream>>>(
      xb, waT, b_attn, (void*)qkv, (int)M, C3, CC);

  attn_kernel<<<dim3(SS / 64, 6, 4), 256, 0, stream>>>(qkv, aout);

  gemm_bt_kernel<0><<<dim3(CC / 64, M / 64), 256, 0, stream>>>(
      aout, wpT, b_proj, (void*)out, (int)M, CC, CC);
}

// Round 5
// 312.346 us; speedup vs baseline: 1.6390x; 1.6357x over previous
//
#include <hip/hip_runtime.h>
#include <hip/hip_bf16.h>
#include <stdint.h>

// CausalMultiHeadAttention: B=4 S=2048 C=768 H=6 D=128
// cast(x,wT) -> GEMM1(LDS-tiled) -> V-transpose -> flash-attn(queue, no-barrier KV loop) -> GEMM2
#define SS 2048
#define CC 768
#define C3 2304
#define NITEMS (32 * 24)

typedef float f32x4 __attribute__((ext_vector_type(4)));
typedef short s16x8 __attribute__((ext_vector_type(8)));

__device__ __forceinline__ unsigned short f2bf(float f) {
  union { float f; unsigned int u; } v; v.f = f;
  unsigned int r = (v.u + 0x7FFFu + ((v.u >> 16) & 1u)) >> 16;
  return (unsigned short)r;
}

__device__ __forceinline__ s16x8 ld8(const unsigned short* p) {
  return *reinterpret_cast<const s16x8*>(p);
}

__device__ __forceinline__ unsigned int cvt_pk_bf16(float lo, float hi) {
  unsigned int r;
  asm("v_cvt_pk_bf16_f32 %0, %1, %2" : "=v"(r) : "v"(lo), "v"(hi));
  return r;
}

__global__ __launch_bounds__(256) void cast_bf16_kernel(
    const float* __restrict__ src, unsigned short* __restrict__ dst, int n4) {
  int i = blockIdx.x * 256 + threadIdx.x;
  if (i < n4) {
    float4 v = reinterpret_cast<const float4*>(src)[i];
    ushort4 o;
    o.x = f2bf(v.x); o.y = f2bf(v.y); o.z = f2bf(v.z); o.w = f2bf(v.w);
    reinterpret_cast<ushort4*>(dst)[i] = o;
  }
}

// src [R][C] f32 -> dst [C][R] bf16
__global__ __launch_bounds__(256) void transpose_cast_kernel(
    const float* __restrict__ src, unsigned short* __restrict__ dst, int R, int C) {
  __shared__ float tile[32][33];
  int c0 = blockIdx.x * 32, r0 = blockIdx.y * 32;
  int tx = threadIdx.x & 31, ty = threadIdx.x >> 5;
  #pragma unroll
  for (int i = 0; i < 32; i += 8)
    tile[ty + i][tx] = src[(size_t)(r0 + ty + i) * C + c0 + tx];
  __syncthreads();
  #pragma unroll
  for (int i = 0; i < 32; i += 8)
    dst[(size_t)(c0 + ty + i) * R + r0 + tx] = f2bf(tile[tx][ty + i]);
}

// V region of qkv [token][C3] -> vT [bh][d=128][n=S], 64x128 tiles via swizzled LDS
__global__ __launch_bounds__(256) void vtrans_kernel(
    const unsigned short* __restrict__ qkv, unsigned short* __restrict__ vT) {
  __shared__ unsigned short t[64 * 128];
  const int tid = threadIdx.x;
  const int n0 = blockIdx.x * 64;
  const int bh = blockIdx.y;
  const int b = bh / 6, h = bh % 6;
  #pragma unroll
  for (int it = 0; it < 4; ++it) {
    int c = it * 256 + tid;
    int n = c >> 4, slot = c & 15;
    s16x8 v = ld8(qkv + (size_t)(b * SS + n0 + n) * C3 + 2 * CC + h * 128 + slot * 8);
    int ss = slot ^ ((n >> 3) & 7);
    *reinterpret_cast<s16x8*>(&t[n * 128 + ss * 8]) = v;
  }
  __syncthreads();
  #pragma unroll
  for (int it = 0; it < 4; ++it) {
    int c = it * 256 + tid;
    int d = c >> 3, n8 = (c & 7) * 8;
    s16x8 o;
    #pragma unroll
    for (int j = 0; j < 8; ++j) {
      int n = n8 + j;
      int sl = (d >> 3) ^ ((n >> 3) & 7);
      o[j] = (short)t[n * 128 + sl * 8 + (d & 7)];
    }
    *reinterpret_cast<s16x8*>(&vT[((size_t)bh * 128 + d) * SS + n0 + n8]) = o;
  }
}

// C[m][n] = sum_k A[m][k]*Bt[n][k] + bias[n].  128x128 tile, BK=32, LDS-staged.
// 4 waves (2x2), each wave 64x64 = 4x4 MFMA 16x16x32 frags.
template <int OUT_BF16>
__global__ __launch_bounds__(256) void gemm_lds_kernel(
    const unsigned short* __restrict__ A, const unsigned short* __restrict__ Bt,
    const float* __restrict__ bias, void* __restrict__ out, int M, int N, int K) {
  __shared__ unsigned short lA[128 * 32];
  __shared__ unsigned short lB[128 * 32];
  const int tid = threadIdx.x, lane = tid & 63, w = tid >> 6;
  const int m0 = blockIdx.y * 128, n0 = blockIdx.x * 128;
  const int lm = lane & 15, lg = lane >> 4;
  const int wm = (w >> 1) * 64, wn = (w & 1) * 64;
  // staging: chunk c covers LDS elems [c*8, c*8+8) = row c>>2, k-slot (c&3)*8
  const int rS = tid >> 2, sl = (tid & 3) * 8;
  const unsigned short* gA0 = A + (size_t)(m0 + rS) * K + sl;
  const unsigned short* gA1 = A + (size_t)(m0 + rS + 64) * K + sl;
  const unsigned short* gB0 = Bt + (size_t)(n0 + rS) * K + sl;
  const unsigned short* gB1 = Bt + (size_t)(n0 + rS + 64) * K + sl;
  unsigned short* dA0 = &lA[tid * 8];
  unsigned short* dA1 = &lA[(tid + 256) * 8];
  unsigned short* dB0 = &lB[tid * 8];
  unsigned short* dB1 = &lB[(tid + 256) * 8];
  int aOff[4], bOff[4];
  #pragma unroll
  for (int i = 0; i < 4; ++i) {
    aOff[i] = (wm + i * 16 + lm) * 32 + lg * 8;
    bOff[i] = (wn + i * 16 + lm) * 32 + lg * 8;
  }
  f32x4 acc[4][4] = {};
  for (int k0 = 0; k0 < K; k0 += 32) {
    s16x8 ra0 = ld8(gA0 + k0), ra1 = ld8(gA1 + k0);
    s16x8 rb0 = ld8(gB0 + k0), rb1 = ld8(gB1 + k0);
    __syncthreads();
    *reinterpret_cast<s16x8*>(dA0) = ra0;
    *reinterpret_cast<s16x8*>(dA1) = ra1;
    *reinterpret_cast<s16x8*>(dB0) = rb0;
    *reinterpret_cast<s16x8*>(dB1) = rb1;
    __syncthreads();
    s16x8 af[4], bf[4];
    #pragma unroll
    for (int i = 0; i < 4; ++i) af[i] = ld8(&lA[aOff[i]]);
    #pragma unroll
    for (int i = 0; i < 4; ++i) bf[i] = ld8(&lB[bOff[i]]);
    #pragma unroll
    for (int mi = 0; mi < 4; ++mi)
      #pragma unroll
      for (int ni = 0; ni < 4; ++ni)
        acc[mi][ni] = __builtin_amdgcn_mfma_f32_16x16x32_bf16(af[mi], bf[ni], acc[mi][ni], 0, 0, 0);
  }
  #pragma unroll
  for (int mi = 0; mi < 4; ++mi) {
    #pragma unroll
    for (int ni = 0; ni < 4; ++ni) {
      const int row = m0 + wm + mi * 16 + lg * 4;
      const int col = n0 + wn + ni * 16 + lm;
      const float bs = bias[col];
      #pragma unroll
      for (int r = 0; r < 4; ++r) {
        float v = acc[mi][ni][r] + bs;
        if (OUT_BF16)
          ((unsigned short*)out)[(size_t)(row + r) * N + col] = f2bf(v);
        else
          ((float*)out)[(size_t)(row + r) * N + col] = v;
      }
    }
  }
}

// Flash attention, causal, dynamic work queue.
// Item = (bh, 64-row q-tile), pulled in descending-cost (qt) order.
// 4 waves/block, wave owns 16 q-rows. KVBLK=64. K read direct from global,
// V^T read direct from pre-transposed vT. No barriers in the KV loop.
__global__ __launch_bounds__(256) void attn_kernel(
    const unsigned short* __restrict__ qkv,
    const unsigned short* __restrict__ vT,
    unsigned short* __restrict__ aout,
    int* __restrict__ ctr) {
  const int tid = threadIdx.x, lane = tid & 63, w = tid >> 6;
  const int lm = lane & 15, lg = lane >> 4;
  __shared__ unsigned int pb[4][16 * 44];  // per-wave P rows, u32 stride 44
  __shared__ int s_item;
  const float scale = 0.08838834764831845f;  // 1/sqrt(128)
  for (;;) {
    __syncthreads();
    if (tid == 0) s_item = atomicAdd(ctr, 1);
    __syncthreads();
    const int item = s_item;
    if (item >= NITEMS) return;
    const int qt = 31 - (item / 24);  // expensive q-tiles first (LPT)
    const int bh = item % 24;
    const int b = bh / 6, h = bh % 6;
    const int wq0 = qt * 64 + w * 16;
    const unsigned short* base = qkv + (size_t)b * SS * C3;
    const unsigned short* vb = vT + (size_t)bh * 128 * SS;
    s16x8 qf[4];
    {
      const unsigned short* qp = base + (size_t)(wq0 + lm) * C3 + h * 128 + lg * 8;
      #pragma unroll
      for (int ks = 0; ks < 4; ++ks) qf[ks] = ld8(qp + ks * 32);
    }
    f32x4 oacc[8] = {};
    float m_run = -1e30f, l_run = 0.0f;
    for (int n0 = 0; n0 < wq0 + 16; n0 += 64) {
      // QK^T swapped: sacc[nsub] = S^T[n][q], n = n0+nsub*16+lg*4+r, q = lm
      f32x4 sacc[4] = {};
      #pragma unroll
      for (int nsub = 0; nsub < 4; ++nsub) {
        const unsigned short* kp =
            base + (size_t)(n0 + nsub * 16 + lm) * C3 + CC + h * 128 + lg * 8;
        #pragma unroll
        for (int ks = 0; ks < 4; ++ks)
          sacc[nsub] = __builtin_amdgcn_mfma_f32_16x16x32_bf16(ld8(kp + ks * 32), qf[ks], sacc[nsub], 0, 0, 0);
      }
      const int qg = wq0 + lm;
      const bool full = (n0 + 63 <= wq0);
      float xs[4][4];
      float tmax = -1e30f;
      #pragma unroll
      for (int nsub = 0; nsub < 4; ++nsub) {
        #pragma unroll
        for (int r = 0; r < 4; ++r) {
          int n = n0 + nsub * 16 + lg * 4 + r;
          float x = sacc[nsub][r] * scale;
          if (!full && n > qg) x = -1e30f;
          xs[nsub][r] = x;
          tmax = fmaxf(tmax, x);
        }
      }
      tmax = fmaxf(tmax, __shfl_xor(tmax, 16));
      tmax = fmaxf(tmax, __shfl_xor(tmax, 32));
      const float m_new = fmaxf(m_run, tmax);
      float psum = 0.0f;
      unsigned int pk_[4][2];
      #pragma unroll
      for (int nsub = 0; nsub < 4; ++nsub) {
        float p0 = __expf(xs[nsub][0] - m_new);
        float p1 = __expf(xs[nsub][1] - m_new);
        float p2 = __expf(xs[nsub][2] - m_new);
        float p3 = __expf(xs[nsub][3] - m_new);
        psum += (p0 + p1) + (p2 + p3);
        pk_[nsub][0] = cvt_pk_bf16(p0, p1);
        pk_[nsub][1] = cvt_pk_bf16(p2, p3);
      }
      psum += __shfl_xor(psum, 16);
      psum += __shfl_xor(psum, 32);
      const float resc = __expf(m_run - m_new);
      l_run = l_run * resc + psum;
      m_run = m_new;
      float rs[4];
      #pragma unroll
      for (int r = 0; r < 4; ++r) rs[r] = __shfl(resc, lg * 4 + r);
      #pragma unroll
      for (int dsub = 0; dsub < 8; ++dsub)
        #pragma unroll
        for (int r = 0; r < 4; ++r) oacc[dsub][r] *= rs[r];
      // stage P^T -> P rows in per-wave LDS (u32 pairs; row q=lm, cols n)
      unsigned int* pr = &pb[w][lm * 44];
      #pragma unroll
      for (int nsub = 0; nsub < 4; ++nsub) {
        pr[nsub * 8 + lg * 2] = pk_[nsub][0];
        pr[nsub * 8 + lg * 2 + 1] = pk_[nsub][1];
      }
      // PV: A = P[q=lm][n-chunk], B = V^T direct from global (coalesced b128)
      #pragma unroll
      for (int nch = 0; nch < 2; ++nch) {
        s16x8 pf = *reinterpret_cast<const s16x8*>(&pr[nch * 16 + lg * 4]);
        const unsigned short* vp0 = vb + (size_t)lm * SS + n0 + nch * 32 + lg * 8;
        #pragma unroll
        for (int dsub = 0; dsub < 8; ++dsub) {
          s16x8 vf = ld8(vp0 + (size_t)dsub * 16 * SS);
          oacc[dsub] = __builtin_amdgcn_mfma_f32_16x16x32_bf16(pf, vf, oacc[dsub], 0, 0, 0);
        }
      }
    }
    float linv[4];
    #pragma unroll
    for (int r = 0; r < 4; ++r) linv[r] = 1.0f / __shfl(l_run, lg * 4 + r);
    #pragma unroll
    for (int dsub = 0; dsub < 8; ++dsub) {
      const int col = h * 128 + dsub * 16 + lm;
      #pragma unroll
      for (int r = 0; r < 4; ++r)
        aout[(size_t)(b * SS + wq0 + lg * 4 + r) * CC + col] =
            f2bf(oacc[dsub][r] * linv[r]);
    }
  }
}

extern "C" void kernel_launch(void* const* d_in, const int* in_sizes, int n_in,
                              void* d_out, int out_size, void* d_ws, size_t ws_size,
                              hipStream_t stream) {
  const float* x      = (const float*)d_in[0];
  const float* w_attn = (const float*)d_in[1];
  const float* b_attn = (const float*)d_in[2];
  const float* w_proj = (const float*)d_in[3];
  const float* b_proj = (const float*)d_in[4];
  float* out = (float*)d_out;

  const size_t M = 4 * (size_t)SS;  // 8192 tokens
  unsigned short* ws = (unsigned short*)d_ws;
  unsigned short* xb   = ws;                        // [8192,768] (dead after GEMM1)
  unsigned short* waT  = xb + M * CC;               // [2304,768]
  unsigned short* wpT  = waT + (size_t)C3 * CC;     // [768,768]
  unsigned short* qkv  = wpT + (size_t)CC * CC;     // [8192,2304]
  unsigned short* aout = qkv + M * C3;              // [8192,768]
  unsigned short* vT   = xb;                        // [24,128,2048] aliases dead xb
  int* ctr = (int*)(aout + M * CC);

  int n4 = (int)(M * CC / 4);
  cast_bf16_kernel<<<(n4 + 255) / 256, 256, 0, stream>>>(x, xb, n4);
  transpose_cast_kernel<<<dim3(C3 / 32, CC / 32), 256, 0, stream>>>(w_attn, waT, CC, C3);
  transpose_cast_kernel<<<dim3(CC / 32, CC / 32), 256, 0, stream>>>(w_proj, wpT, CC, CC);

  gemm_lds_kernel<1><<<dim3(C3 / 128, M / 128), 256, 0, stream>>>(
      xb, waT, b_attn, (void*)qkv, (int)M, C3, CC);

  vtrans_kernel<<<dim3(SS / 64, 24), 256, 0, stream>>>(qkv, vT);

  hipMemsetAsync(ctr, 0, sizeof(int), stream);
  attn_kernel<<<512, 256, 0, stream>>>(qkv, vT, aout, ctr);

  gemm_lds_kernel<0><<<dim3(CC / 128, M / 128), 256, 0, stream>>>(
      aout, wpT, b_proj, (void*)out, (int)M, CC, CC);
}